// Round 1
// baseline (94.816 us; speedup 1.0000x reference)
//
#include <hip/hip_runtime.h>
#include <math.h>

// CLIF spiking recurrence, [T=64, B=128, D=4096] fp32.
// One thread per 4 consecutive neurons (float4 loads/stores, 16B/lane).
// State ops replicate fp32 reference semantics exactly:
//   - 0.5f*u is exact (binary FP), single-rounded add via __fadd_rn
//   - spike test (u - 1 >= 0) == (u >= 1) exactly (Sterbenz)
//   - no FMA contraction anywhere (_rn intrinsics)
// Sigmoid computed correctly-rounded to fp32 via f64 exp (round-1: correctness
// first; will swap to cheap f64 poly-exp2 preserving identical fp32 results).

#define T_STEPS 64
#define BD      (128 * 4096)   // 524288 neurons
#define N4      (BD / 4)       // 131072 threads

__device__ __forceinline__ float sigmoid_cr(float x) {
    // correctly-rounded fp32 sigmoid (f64 internal)
    double e = exp(-(double)x);
    return (float)(1.0 / (1.0 + e));
}

__device__ __forceinline__ float clif_step(float& u, float& m, float x) {
    // u = gamma*u + x  (gamma = 0.5, mul exact, one rounding in add)
    u = __fadd_rn(__fmul_rn(0.5f, u), x);
    // spike = heaviside(u - V_TH); fl(u-1)>=0  <=>  u>=1
    float spike = (u >= 1.0f) ? 1.0f : 0.0f;
    // m = m * sigmoid((1-gamma)*u) + spike   (0.5f*u exact)
    float s1 = sigmoid_cr(__fmul_rn(0.5f, u));
    float mn = __fadd_rn(__fmul_rn(m, s1), spike);
    // sm = sigmoid(m); carried as next m (in-place sigmoid_ semantics)
    float sm = sigmoid_cr(mn);
    // u = u - spike * (V_TH + sm)
    u = __fsub_rn(u, __fmul_rn(spike, __fadd_rn(1.0f, sm)));
    m = sm;
    return spike;
}

__global__ __launch_bounds__(256) void clif_kernel(const float4* __restrict__ x4,
                                                   float4* __restrict__ o4) {
    int gid = blockIdx.x * blockDim.x + threadIdx.x;  // 0 .. N4-1
    if (gid >= N4) return;

    float u0 = 0.f, u1 = 0.f, u2 = 0.f, u3 = 0.f;
    float m0 = 0.f, m1 = 0.f, m2 = 0.f, m3 = 0.f;

    #pragma unroll 1
    for (int t = 0; t < T_STEPS; ++t) {
        float4 xv = x4[(size_t)t * N4 + gid];
        float4 sp;
        sp.x = clif_step(u0, m0, xv.x);
        sp.y = clif_step(u1, m1, xv.y);
        sp.z = clif_step(u2, m2, xv.z);
        sp.w = clif_step(u3, m3, xv.w);
        o4[(size_t)t * N4 + gid] = sp;
    }
}

extern "C" void kernel_launch(void* const* d_in, const int* in_sizes, int n_in,
                              void* d_out, int out_size, void* d_ws, size_t ws_size,
                              hipStream_t stream) {
    const float4* x = (const float4*)d_in[0];
    float4* out = (float4*)d_out;
    dim3 block(256);
    dim3 grid(N4 / 256);  // 512 blocks, 2048 waves, 8 waves/CU
    clif_kernel<<<grid, block, 0, stream>>>(x, out);
}

// Round 2
// 75.158 us; speedup vs baseline: 1.2616x; 1.2616x over previous
//
#include <hip/hip_runtime.h>
#include <math.h>

// CLIF spiking recurrence, [T=64, B=128, D=4096] fp32.
// One thread per 4 consecutive neurons (float4 loads/stores, 16B/lane).
//
// State ops replicate fp32 reference semantics exactly (see R1: absmax 0.0):
//   - 0.5f*u exact, single-rounded ops via __f*_rn (no contraction)
//   - spike test (u - 1 >= 0) == (u >= 1) exactly (Sterbenz)
//
// Sigmoid: custom f64 path producing a CORRECTLY-ROUNDED fp32 result
// (rel err ~3e-13 << half-ulp 3e-8), ~22 f64 ops vs libm exp's ~50+:
//   t = -x*log2(e); n = rint(t) via 2^52+2^51 magic; f = t - n
//   2^f = e^(f*ln2), deg-10 Taylor Horner (trunc err 2.2e-13)
//   e = 2^f * 2^n (exponent-bit construct), d = 1 + e
//   1/d via v_rcp_f32 seed + 2 f64 Newton steps (err -> ~f64 eps)
// Expected spike flips vs reference: ~1e-3 (analysis in journal) -> absmax 0.

#define T_STEPS 64
#define BD      (128 * 4096)   // 524288 neurons
#define N4      (BD / 4)       // 131072 threads

__device__ __forceinline__ float sigmoid_cr(float x) {
    const double SHIFT = 6755399441055744.0;     // 2^52 + 2^51
    double xd = (double)x;
    double t  = xd * -1.4426950408889634;        // -x * log2(e)
    double tn = t + SHIFT;                       // rint via magic add (RNE)
    int    n  = __double2loint(tn);              // low 32 bits = n (2's comp)
    double f  = t - (tn - SHIFT);                // f in [-0.5, 0.5]
    double y  = f * 0.6931471805599453;          // f * ln2, y in [-0.347, 0.347]
    // e^y, degree-10 Taylor (Horner, 10 FMA); trunc err ~2.2e-13 rel
    double p = 2.755731922398589e-7;             // 1/10!
    p = fma(p, y, 2.755731922398589e-6);         // 1/9!
    p = fma(p, y, 2.480158730158730e-5);         // 1/8!
    p = fma(p, y, 1.984126984126984e-4);         // 1/7!
    p = fma(p, y, 1.388888888888889e-3);         // 1/6!
    p = fma(p, y, 8.333333333333333e-3);         // 1/5!
    p = fma(p, y, 4.166666666666666e-2);         // 1/4!
    p = fma(p, y, 1.666666666666667e-1);         // 1/3!
    p = fma(p, y, 0.5);                          // 1/2!
    p = fma(p, y, 1.0);
    p = fma(p, y, 1.0);
    // scale by 2^n: n bounded ~[-20,20] for this data (|x| <~ 13)
    double sc = __hiloint2double(0x3FF00000 + ((unsigned)n << 20), 0);
    double e  = p * sc;                          // e^{ -x }
    double d  = 1.0 + e;
    // reciprocal: f32 rcp seed (1 ulp) + 2 Newton iters in f64
    double r = (double)__builtin_amdgcn_rcpf((float)d);
    r = r * fma(-d, r, 2.0);                     // err ~ 4e-14
    r = r * fma(-d, r, 2.0);                     // err ~ f64 eps
    return (float)r;
}

__device__ __forceinline__ float clif_step(float& u, float& m, float x) {
    // u = 0.5*u + x  (mul exact, one rounding in add)
    u = __fadd_rn(__fmul_rn(0.5f, u), x);
    float spike = (u >= 1.0f) ? 1.0f : 0.0f;
    // m = m * sigmoid(0.5*u) + spike   (0.5f*u exact)
    float s1 = sigmoid_cr(__fmul_rn(0.5f, u));
    float mn = __fadd_rn(__fmul_rn(m, s1), spike);
    // sm = sigmoid(m); carried as next m (in-place sigmoid_ semantics)
    float sm = sigmoid_cr(mn);
    // u = u - spike * (1 + sm)
    u = __fsub_rn(u, __fmul_rn(spike, __fadd_rn(1.0f, sm)));
    m = sm;
    return spike;
}

__global__ __launch_bounds__(256) void clif_kernel(const float4* __restrict__ x4,
                                                   float4* __restrict__ o4) {
    int gid = blockIdx.x * blockDim.x + threadIdx.x;  // 0 .. N4-1

    float u0 = 0.f, u1 = 0.f, u2 = 0.f, u3 = 0.f;
    float m0 = 0.f, m1 = 0.f, m2 = 0.f, m3 = 0.f;

    float4 xv = x4[gid];  // prefetch t=0
    #pragma unroll 1
    for (int t = 0; t < T_STEPS; ++t) {
        float4 xn;
        if (t + 1 < T_STEPS)
            xn = x4[(size_t)(t + 1) * N4 + gid];   // prefetch next t under compute
        float4 sp;
        sp.x = clif_step(u0, m0, xv.x);
        sp.y = clif_step(u1, m1, xv.y);
        sp.z = clif_step(u2, m2, xv.z);
        sp.w = clif_step(u3, m3, xv.w);
        o4[(size_t)t * N4 + gid] = sp;
        xv = xn;
    }
}

extern "C" void kernel_launch(void* const* d_in, const int* in_sizes, int n_in,
                              void* d_out, int out_size, void* d_ws, size_t ws_size,
                              hipStream_t stream) {
    const float4* x = (const float4*)d_in[0];
    float4* out = (float4*)d_out;
    dim3 block(256);
    dim3 grid(N4 / 256);  // 512 blocks, 8 waves/CU
    clif_kernel<<<grid, block, 0, stream>>>(x, out);
}

// Round 3
// 70.643 us; speedup vs baseline: 1.3422x; 1.0639x over previous
//
#include <hip/hip_runtime.h>
#include <math.h>

// CLIF spiking recurrence, [T=64, B=128, D=4096] fp32.
// R3: one NEURON per thread (scalar loads). 524288 threads = 8192 waves =
// 8 waves/SIMD -> wave-level latency hiding for the serial f64 FMA chain
// (R2 showed the compiler refuses to interleave per-thread element chains:
// VGPR=20, VALUBusy 53%, latency-bound).
//
// State ops replicate fp32 reference semantics exactly (R1/R2: absmax 0.0):
//   - 0.5f*u exact, single-rounded ops via __f*_rn (no contraction)
//   - spike test (u - 1 >= 0) == (u >= 1) exactly (Sterbenz)
//
// Sigmoid: f64 path, fp32 result correctly rounded (rel err ~3e-13):
//   magic-add rint range reduction, deg-10 Taylor Horner for e^y,
//   exponent-bit 2^n scale, recip = v_rcp_f32 seed + ONE f64 Newton
//   (seed err 6e-8 -> squared 4e-15 << poly trunc 2.2e-13; 2nd step was
//   redundant). 19 f64 ops/sigmoid.

#define T_STEPS 64
#define BD      (128 * 4096)   // 524288 neurons

__device__ __forceinline__ float sigmoid_cr(float x) {
    const double SHIFT = 6755399441055744.0;     // 2^52 + 2^51
    double t  = (double)x * -1.4426950408889634; // -x * log2(e)
    double tn = t + SHIFT;                       // rint via magic add (RNE)
    int    n  = __double2loint(tn);              // low 32 bits = n (2's comp)
    double f  = t - (tn - SHIFT);                // f in [-0.5, 0.5]
    double y  = f * 0.6931471805599453;          // f * ln2, |y| <= 0.3466
    // e^y, degree-10 Taylor (Horner, 10 FMA); trunc err ~2.2e-13 rel
    double p = 2.755731922398589e-7;             // 1/10!
    p = fma(p, y, 2.755731922398589e-6);         // 1/9!
    p = fma(p, y, 2.480158730158730e-5);         // 1/8!
    p = fma(p, y, 1.984126984126984e-4);         // 1/7!
    p = fma(p, y, 1.388888888888889e-3);         // 1/6!
    p = fma(p, y, 8.333333333333333e-3);         // 1/5!
    p = fma(p, y, 4.166666666666666e-2);         // 1/4!
    p = fma(p, y, 1.666666666666667e-1);         // 1/3!
    p = fma(p, y, 0.5);                          // 1/2!
    p = fma(p, y, 1.0);
    p = fma(p, y, 1.0);
    // scale by 2^n (n bounded ~[-20,20] for this data)
    double sc = __hiloint2double(0x3FF00000 + ((unsigned)n << 20), 0);
    double e  = p * sc;                          // e^{-x}
    double d  = 1.0 + e;
    // reciprocal: f32 rcp seed (err ~6e-8) + 1 f64 Newton -> err ~4e-15
    double r = (double)__builtin_amdgcn_rcpf((float)d);
    r = r * fma(-d, r, 2.0);
    return (float)r;
}

__device__ __forceinline__ float clif_step(float& u, float& m, float x) {
    // u = 0.5*u + x  (mul exact, one rounding in add)
    u = __fadd_rn(__fmul_rn(0.5f, u), x);
    float spike = (u >= 1.0f) ? 1.0f : 0.0f;
    // m = m * sigmoid(0.5*u) + spike   (0.5f*u exact)
    float s1 = sigmoid_cr(__fmul_rn(0.5f, u));
    float mn = __fadd_rn(__fmul_rn(m, s1), spike);
    // sm = sigmoid(m); carried as next m (in-place sigmoid_ semantics)
    float sm = sigmoid_cr(mn);
    // u = u - spike * (1 + sm)
    u = __fsub_rn(u, __fmul_rn(spike, __fadd_rn(1.0f, sm)));
    m = sm;
    return spike;
}

__global__ __launch_bounds__(256, 8) void clif_kernel(const float* __restrict__ x,
                                                      float* __restrict__ o) {
    int gid = blockIdx.x * blockDim.x + threadIdx.x;  // 0 .. BD-1

    float u = 0.f, m = 0.f;
    float xv = x[gid];  // prefetch t=0
    #pragma unroll 1
    for (int t = 0; t < T_STEPS; ++t) {
        float xn;
        if (t + 1 < T_STEPS)
            xn = x[(size_t)(t + 1) * BD + gid];   // prefetch next t under compute
        float sp = clif_step(u, m, xv);
        o[(size_t)t * BD + gid] = sp;
        xv = xn;
    }
}

extern "C" void kernel_launch(void* const* d_in, const int* in_sizes, int n_in,
                              void* d_out, int out_size, void* d_ws, size_t ws_size,
                              hipStream_t stream) {
    const float* x = (const float*)d_in[0];
    float* out = (float*)d_out;
    dim3 block(256);
    dim3 grid(BD / 256);  // 2048 blocks -> 8192 waves -> 8 waves/SIMD
    clif_kernel<<<grid, block, 0, stream>>>(x, out);
}

// Round 4
// 69.036 us; speedup vs baseline: 1.3734x; 1.0233x over previous
//
#include <hip/hip_runtime.h>
#include <math.h>

// CLIF spiking recurrence, [T=64, B=128, D=4096] fp32.
// One neuron per thread; 524288 threads = 8192 waves = 8 waves/SIMD (max).
//
// NUMERICS FROZEN (R1-R3: absmax 0.0):
//   - state chain in f32 with single-rounded __f*_rn ops, no contraction
//   - spike test (u >= 1.0f) == fl(u-1) >= 0 (Sterbenz)
//   - sigmoid: f64 path, fp32 result correctly rounded (rel err ~3e-13):
//     magic-add rint range reduction, y = f*ln2, deg-10 Taylor Horner,
//     exponent-bit 2^n scale, recip = v_rcp_f32 seed + 1 f64 Newton.
//   Spike gating via select (spike in {0,1}) -> bit-identical to multiply.
//
// R4: t-loop unrolled x2, 2-deep branch-free prefetch (clamped uniform
// index), nontemporal output stores (output never read; keep input L3-hot).

#define T_STEPS 64
#define BD      (128 * 4096)   // 524288 neurons

__device__ __forceinline__ float sigmoid_cr(float x) {
    const double SHIFT = 6755399441055744.0;     // 2^52 + 2^51
    double t  = (double)x * -1.4426950408889634; // -x * log2(e)
    double tn = t + SHIFT;                       // rint via magic add (RNE)
    int    n  = __double2loint(tn);              // low 32 bits = n (2's comp)
    double f  = t - (tn - SHIFT);                // f in [-0.5, 0.5]
    double y  = f * 0.6931471805599453;          // f * ln2, |y| <= 0.3466
    // e^y, degree-10 Taylor (Horner); trunc err ~2.2e-13 rel
    double p = 2.755731922398589e-7;             // 1/10!
    p = fma(p, y, 2.755731922398589e-6);         // 1/9!
    p = fma(p, y, 2.480158730158730e-5);         // 1/8!
    p = fma(p, y, 1.984126984126984e-4);         // 1/7!
    p = fma(p, y, 1.388888888888889e-3);         // 1/6!
    p = fma(p, y, 8.333333333333333e-3);         // 1/5!
    p = fma(p, y, 4.166666666666666e-2);         // 1/4!
    p = fma(p, y, 1.666666666666667e-1);         // 1/3!
    p = fma(p, y, 0.5);                          // 1/2!
    p = fma(p, y, 1.0);
    p = fma(p, y, 1.0);
    // scale by 2^n (n bounded ~[-20,20] for this data)
    double sc = __hiloint2double(0x3FF00000 + ((unsigned)n << 20), 0);
    double e  = p * sc;                          // e^{-x}
    double d  = 1.0 + e;
    // reciprocal: f32 rcp seed (err ~6e-8) + 1 f64 Newton -> err ~4e-15
    double r = (double)__builtin_amdgcn_rcpf((float)d);
    r = r * fma(-d, r, 2.0);
    return (float)r;
}

__device__ __forceinline__ float clif_step(float& u, float& m, float x) {
    // u = 0.5*u + x  (mul exact, one rounding in add)
    u = __fadd_rn(__fmul_rn(0.5f, u), x);
    bool spike = (u >= 1.0f);
    // m = m * sigmoid(0.5*u) + spike   (0.5f*u exact; +1 via select, identical)
    float s1  = sigmoid_cr(__fmul_rn(0.5f, u));
    float ms1 = __fmul_rn(m, s1);
    float mn  = spike ? __fadd_rn(ms1, 1.0f) : ms1;
    // sm = sigmoid(m); carried as next m (in-place sigmoid_ semantics)
    float sm = sigmoid_cr(mn);
    // u = u - spike * (1 + sm)  (select form, bit-identical)
    u = spike ? __fsub_rn(u, __fadd_rn(1.0f, sm)) : u;
    m = sm;
    return spike ? 1.0f : 0.0f;
}

__global__ __launch_bounds__(256, 8) void clif_kernel(const float* __restrict__ x,
                                                      float* __restrict__ o) {
    int gid = blockIdx.x * blockDim.x + threadIdx.x;  // 0 .. BD-1
    const float* xp = x + gid;
    float*       op = o + gid;

    float u = 0.f, m = 0.f;
    float xa = xp[0];                       // prefetch t=0
    float xb = xp[(size_t)BD];              // prefetch t=1

    #pragma unroll 1
    for (int t = 0; t < T_STEPS; t += 2) {
        // branch-free 2-deep prefetch (uniform clamped scalar indices)
        int i2 = min(t + 2, T_STEPS - 1);
        int i3 = min(t + 3, T_STEPS - 1);
        float xc = xp[(size_t)i2 * BD];
        float xd = xp[(size_t)i3 * BD];

        float s0 = clif_step(u, m, xa);
        float s1v = clif_step(u, m, xb);

        __builtin_nontemporal_store(s0,  op + (size_t)t * BD);
        __builtin_nontemporal_store(s1v, op + (size_t)(t + 1) * BD);

        xa = xc;
        xb = xd;
    }
}

extern "C" void kernel_launch(void* const* d_in, const int* in_sizes, int n_in,
                              void* d_out, int out_size, void* d_ws, size_t ws_size,
                              hipStream_t stream) {
    const float* x = (const float*)d_in[0];
    float* out = (float*)d_out;
    dim3 block(256);
    dim3 grid(BD / 256);  // 2048 blocks -> 8 blocks/CU -> 32 waves/CU (max)
    clif_kernel<<<grid, block, 0, stream>>>(x, out);
}

// Round 5
// 65.507 us; speedup vs baseline: 1.4474x; 1.0539x over previous
//
#include <hip/hip_runtime.h>
#include <math.h>

// CLIF spiking recurrence, [T=64, B=128, D=4096] fp32.
// One neuron per thread; 524288 threads = 8192 waves = 8 waves/SIMD (max).
//
// NUMERICS (R1-R4: absmax 0.0, frozen modulo deg-10->9 trim):
//   - state chain in f32 with single-rounded __f*_rn ops, no contraction
//   - spike test (u >= 1.0f) == fl(u-1) >= 0 (Sterbenz)
//   - sigmoid: f64 path, fp32 result correctly rounded (rel err ~1e-11):
//     magic-add rint range reduction, y = f*ln2, deg-9 Taylor Horner
//     (trunc 9.7e-12 -> expected spike flips ~1.5e-4, statistically exact),
//     exponent-bit 2^n scale, recip = v_rcp_f32 seed + 1 f64 Newton.
//   - spike gating via select (spike in {0,1}) -> bit-identical to multiply
//
// R5: 4-deep prefetch ring + t-loop unroll x4 — loads issued ~880 cycles
// ahead of consumption to cover L3/HBM latency (R4 showed ~20% VALU-idle
// from 2-deep prefetch ~ L3 latency). Nontemporal output stores.

#define T_STEPS 64
#define BD      (128 * 4096)   // 524288 neurons

__device__ __forceinline__ float sigmoid_cr(float x) {
    const double SHIFT = 6755399441055744.0;     // 2^52 + 2^51
    double t  = (double)x * -1.4426950408889634; // -x * log2(e)
    double tn = t + SHIFT;                       // rint via magic add (RNE)
    int    n  = __double2loint(tn);              // low 32 bits = n (2's comp)
    double f  = t - (tn - SHIFT);                // f in [-0.5, 0.5]
    double y  = f * 0.6931471805599453;          // f * ln2, |y| <= 0.3466
    // e^y, degree-9 Taylor (Horner); trunc err ~9.7e-12 rel
    double p = 2.755731922398589e-6;             // 1/9!
    p = fma(p, y, 2.480158730158730e-5);         // 1/8!
    p = fma(p, y, 1.984126984126984e-4);         // 1/7!
    p = fma(p, y, 1.388888888888889e-3);         // 1/6!
    p = fma(p, y, 8.333333333333333e-3);         // 1/5!
    p = fma(p, y, 4.166666666666666e-2);         // 1/4!
    p = fma(p, y, 1.666666666666667e-1);         // 1/3!
    p = fma(p, y, 0.5);                          // 1/2!
    p = fma(p, y, 1.0);
    p = fma(p, y, 1.0);
    // scale by 2^n (n bounded ~[-20,20] for this data)
    double sc = __hiloint2double(0x3FF00000 + ((unsigned)n << 20), 0);
    double e  = p * sc;                          // e^{-x}
    double d  = 1.0 + e;
    // reciprocal: f32 rcp seed (err ~6e-8) + 1 f64 Newton -> err ~4e-15
    double r = (double)__builtin_amdgcn_rcpf((float)d);
    r = r * fma(-d, r, 2.0);
    return (float)r;
}

__device__ __forceinline__ float clif_step(float& u, float& m, float x) {
    // u = 0.5*u + x  (mul exact, one rounding in add)
    u = __fadd_rn(__fmul_rn(0.5f, u), x);
    bool spike = (u >= 1.0f);
    // m = m * sigmoid(0.5*u) + spike   (0.5f*u exact; +1 via select, identical)
    float s1  = sigmoid_cr(__fmul_rn(0.5f, u));
    float ms1 = __fmul_rn(m, s1);
    float mn  = spike ? __fadd_rn(ms1, 1.0f) : ms1;
    // sm = sigmoid(m); carried as next m (in-place sigmoid_ semantics)
    float sm = sigmoid_cr(mn);
    // u = u - spike * (1 + sm)  (select form, bit-identical)
    u = spike ? __fsub_rn(u, __fadd_rn(1.0f, sm)) : u;
    m = sm;
    return spike ? 1.0f : 0.0f;
}

__global__ __launch_bounds__(256, 8) void clif_kernel(const float* __restrict__ x,
                                                      float* __restrict__ o) {
    int gid = blockIdx.x * blockDim.x + threadIdx.x;  // 0 .. BD-1
    const float* xp = x + gid;
    float*       op = o + gid;

    float u = 0.f, m = 0.f;
    // 4-deep prefetch ring
    float xa = xp[0];
    float xb = xp[(size_t)BD];
    float xc = xp[(size_t)2 * BD];
    float xd = xp[(size_t)3 * BD];

    #pragma unroll 1
    for (int t = 0; t < T_STEPS; t += 4) {
        // branch-free 4-deep prefetch (uniform clamped scalar indices)
        int i4 = min(t + 4, T_STEPS - 1);
        int i5 = min(t + 5, T_STEPS - 1);
        int i6 = min(t + 6, T_STEPS - 1);
        int i7 = min(t + 7, T_STEPS - 1);
        float n0 = xp[(size_t)i4 * BD];
        float n1 = xp[(size_t)i5 * BD];
        float n2 = xp[(size_t)i6 * BD];
        float n3 = xp[(size_t)i7 * BD];

        float s0 = clif_step(u, m, xa);
        __builtin_nontemporal_store(s0, op + (size_t)t * BD);
        float s1v = clif_step(u, m, xb);
        __builtin_nontemporal_store(s1v, op + (size_t)(t + 1) * BD);
        float s2 = clif_step(u, m, xc);
        __builtin_nontemporal_store(s2, op + (size_t)(t + 2) * BD);
        float s3 = clif_step(u, m, xd);
        __builtin_nontemporal_store(s3, op + (size_t)(t + 3) * BD);

        xa = n0; xb = n1; xc = n2; xd = n3;
    }
}

extern "C" void kernel_launch(void* const* d_in, const int* in_sizes, int n_in,
                              void* d_out, int out_size, void* d_ws, size_t ws_size,
                              hipStream_t stream) {
    const float* x = (const float*)d_in[0];
    float* out = (float*)d_out;
    dim3 block(256);
    dim3 grid(BD / 256);  // 2048 blocks -> 8 blocks/CU -> 32 waves/CU (max)
    clif_kernel<<<grid, block, 0, stream>>>(x, out);
}

// Round 6
// 64.852 us; speedup vs baseline: 1.4620x; 1.0101x over previous
//
#include <hip/hip_runtime.h>
#include <math.h>

// CLIF spiking recurrence, [T=64, B=128, D=4096] fp32.
// One neuron per thread; 524288 threads = 8192 waves = 8 waves/SIMD (max).
//
// NUMERICS (R1-R5: absmax 0.0):
//   - state chain in f32 with single-rounded __f*_rn ops, no contraction
//   - spike test (u >= 1.0f) == fl(u-1) >= 0 (Sterbenz)
//   - spike gating via select (spike in {0,1}) -> bit-identical to multiply
//   - sigmoid: f64 path, fp32 result correctly rounded. R6 form:
//       t = -x*64*log2(e); n = rint(t) (magic add); f = t - n in [-1/2,1/2]
//       y = f*ln2/64, |y| <= 0.00542 -> deg-4 Taylor, trunc err 4e-14
//       e^-x = poly * tab[n&63] * 2^(n>>6)   (exponent-field int add)
//       tab[j] = 2^(j/64) f64, LDS (512 B), init once/block via deg-15 Horner
//       recip = v_rcp_f32 seed + 1 f64 Newton (err ~4e-15)
//     Total sigmoid rel err ~5e-14 (vs 9.7e-12 in R5, which passed absmax 0).
//
// R6 rationale: R5 is f64-pipe issue-bound (~54us busy of 65.5us wall);
// table cuts ~7 f64 ops/sigmoid (~35% of f64 work), gather goes to LDS pipe.

#define T_STEPS 64
#define BD      (128 * 4096)   // 524288 neurons

__device__ __forceinline__ float sigmoid_cr(float x, const double* __restrict__ tab) {
    const double SHIFT = 6755399441055744.0;       // 2^52 + 2^51
    double t  = (double)x * -92.33248261689366;    // -64*log2(e)
    double tn = t + SHIFT;                         // rint via magic add (RNE)
    int    n  = __double2loint(tn);                // n = rint(t), 2's comp
    double f  = t - (tn - SHIFT);                  // exact, f in [-0.5, 0.5]
    double y  = f * (0.6931471805599453 / 64.0);   // |y| <= 0.00542
    // e^y, degree-4 Taylor; trunc err ~3.9e-14 rel
    double p = 1.0 / 24.0;
    p = fma(p, y, 1.0 / 6.0);
    p = fma(p, y, 0.5);
    p = fma(p, y, 1.0);
    p = fma(p, y, 1.0);
    // e^-x = p * 2^((n&63)/64) * 2^(n>>6); scale via exponent-field add
    double e0 = p * tab[n & 63];
    e0 = __hiloint2double(__double2hiint(e0) + ((n >> 6) << 20),
                          __double2loint(e0));
    double d  = 1.0 + e0;
    // reciprocal: f32 rcp seed (err ~6e-8) + 1 f64 Newton -> err ~4e-15
    double r = (double)__builtin_amdgcn_rcpf((float)d);
    r = r * fma(-d, r, 2.0);
    return (float)r;
}

__device__ __forceinline__ float clif_step(float& u, float& m, float x,
                                           const double* __restrict__ tab) {
    // u = 0.5*u + x  (mul exact, one rounding in add)
    u = __fadd_rn(__fmul_rn(0.5f, u), x);
    bool spike = (u >= 1.0f);
    // m = m * sigmoid(0.5*u) + spike   (0.5f*u exact; +1 via select)
    float s1  = sigmoid_cr(__fmul_rn(0.5f, u), tab);
    float ms1 = __fmul_rn(m, s1);
    float mn  = spike ? __fadd_rn(ms1, 1.0f) : ms1;
    // sm = sigmoid(m); carried as next m (in-place sigmoid_ semantics)
    float sm = sigmoid_cr(mn, tab);
    // u = u - spike * (1 + sm)  (select form, bit-identical)
    u = spike ? __fsub_rn(u, __fadd_rn(1.0f, sm)) : u;
    m = sm;
    return spike ? 1.0f : 0.0f;
}

__global__ __launch_bounds__(256, 8) void clif_kernel(const float* __restrict__ x,
                                                      float* __restrict__ o) {
    __shared__ double s_tab[64];
    {
        // tab[j] = 2^(j/64) = e^(j*ln2/64), deg-15 f64 Horner (rel err ~3e-15)
        int j = threadIdx.x & 63;
        double y = (double)j * (0.6931471805599453 / 64.0);
        double p = 1.0 / 1307674368000.0;          // 1/15!
        p = fma(p, y, 1.0 / 87178291200.0);        // 1/14!
        p = fma(p, y, 1.0 / 6227020800.0);         // 1/13!
        p = fma(p, y, 1.0 / 479001600.0);          // 1/12!
        p = fma(p, y, 1.0 / 39916800.0);           // 1/11!
        p = fma(p, y, 1.0 / 3628800.0);            // 1/10!
        p = fma(p, y, 1.0 / 362880.0);             // 1/9!
        p = fma(p, y, 1.0 / 40320.0);              // 1/8!
        p = fma(p, y, 1.0 / 5040.0);               // 1/7!
        p = fma(p, y, 1.0 / 720.0);                // 1/6!
        p = fma(p, y, 1.0 / 120.0);                // 1/5!
        p = fma(p, y, 1.0 / 24.0);                 // 1/4!
        p = fma(p, y, 1.0 / 6.0);                  // 1/3!
        p = fma(p, y, 0.5);                        // 1/2!
        p = fma(p, y, 1.0);
        p = fma(p, y, 1.0);
        s_tab[j] = p;   // lanes with same j write identical bits (benign)
    }
    __syncthreads();

    int gid = blockIdx.x * blockDim.x + threadIdx.x;  // 0 .. BD-1
    const float* xp = x + gid;
    float*       op = o + gid;

    float u = 0.f, m = 0.f;
    // 4-deep prefetch ring
    float xa = xp[0];
    float xb = xp[(size_t)BD];
    float xc = xp[(size_t)2 * BD];
    float xd = xp[(size_t)3 * BD];

    #pragma unroll 1
    for (int t = 0; t < T_STEPS; t += 4) {
        // branch-free 4-deep prefetch (uniform clamped scalar indices)
        int i4 = min(t + 4, T_STEPS - 1);
        int i5 = min(t + 5, T_STEPS - 1);
        int i6 = min(t + 6, T_STEPS - 1);
        int i7 = min(t + 7, T_STEPS - 1);
        float n0 = xp[(size_t)i4 * BD];
        float n1 = xp[(size_t)i5 * BD];
        float n2 = xp[(size_t)i6 * BD];
        float n3 = xp[(size_t)i7 * BD];

        float s0 = clif_step(u, m, xa, s_tab);
        __builtin_nontemporal_store(s0, op + (size_t)t * BD);
        float s1v = clif_step(u, m, xb, s_tab);
        __builtin_nontemporal_store(s1v, op + (size_t)(t + 1) * BD);
        float s2 = clif_step(u, m, xc, s_tab);
        __builtin_nontemporal_store(s2, op + (size_t)(t + 2) * BD);
        float s3 = clif_step(u, m, xd, s_tab);
        __builtin_nontemporal_store(s3, op + (size_t)(t + 3) * BD);

        xa = n0; xb = n1; xc = n2; xd = n3;
    }
}

extern "C" void kernel_launch(void* const* d_in, const int* in_sizes, int n_in,
                              void* d_out, int out_size, void* d_ws, size_t ws_size,
                              hipStream_t stream) {
    const float* x = (const float*)d_in[0];
    float* out = (float*)d_out;
    dim3 block(256);
    dim3 grid(BD / 256);  // 2048 blocks -> 8 blocks/CU -> 32 waves/CU (max)
    clif_kernel<<<grid, block, 0, stream>>>(x, out);
}